// Round 8
// baseline (160.401 us; speedup 1.0000x reference)
//
#include <hip/hip_runtime.h>
#include <stdint.h>

// ---------------------------------------------------------------------------
// B=2048, F0=40, D=32, LAYER0=LAYER1=128.  Rows r=b*32+d (65536).
//   phase0: h0[r,s] = relu(sum_{i<40,j<40} X[r,i]X[r,j] W0[i,j,s] + b0[s])
//   phase1: d1[r,s] = relu(sum_{i<40,j<64} X[r,i]NH[r,j] W1[i,j,s] + b1[s])
//   out[b,0:64] = sum_d h0[:,64:128]; out[b,64:192] = sum_d d1
//
// Round-8: BARRIER AMORTIZATION.  r7 (W via LDS, barrier/step) stalled at
// MfmaUtil 33%: the t+2 global load was issued MID-step and the compiler's
// mandatory s_waitcnt vmcnt(0) before s_barrier drained it ~200cyc later --
// 130 serial L2-latency hits with 1 block/CU (the m97 drain mechanism).
// Fix: 5-tile periods (BK=160).  26 barriers total; per-period per-SIMD
// MFMA = 2 waves x 80 x 16.1 = 2576 cyc so fixed costs are <6%.  Loads are
// issued at the TOP of a period and ds_written at the top of the NEXT
// (one full period in flight -> both the ds_write's vmcnt wait and the
// end-of-period drain are ~free).  LDS: Wb dbuf 80KB + NH 36.9 + Xl 20.
// Pipe budget/period: MFMA 2576 (limiter), LDS ~1600, L2 15.5 B/cyc/CU.
// FP16 datapath: A-frag = one v_pk_mul_f16 per pair (xi2 broadcast * packed
// jv).  Loop nest keeps all xi2 indices compile-time (no reg indexing).
// ---------------------------------------------------------------------------

typedef __attribute__((ext_vector_type(8))) _Float16 half8;
typedef __attribute__((ext_vector_type(2))) _Float16 half2v;
typedef __attribute__((ext_vector_type(4))) float f32x4;

__device__ __forceinline__ unsigned short f2h(float f) {   // v_cvt_f16_f32, RNE
    return __builtin_bit_cast(unsigned short, (_Float16)f);
}
__device__ __forceinline__ float qsum(float v) {  // reduce across row-quads
    v += __shfl_xor(v, 16, 64);
    v += __shfl_xor(v, 32, 64);
    return v;
}

// Permute W -> Wp[t][s][kl] fp16, t = jc*10+ic, kl = ii*8+jj, i=ic*4+ii,
// j=jc*8+jj.  One block per tile t; thread = (s, h) writes 32B contiguous.
__global__ void permute_w_both(const float* __restrict__ W0, const float* __restrict__ W1,
                               unsigned short* __restrict__ Wp0, unsigned short* __restrict__ Wp1)
{
    int t = blockIdx.x;
    int s = threadIdx.x >> 1, h = threadIdx.x & 1;
    const float* W; unsigned short* Wp; int JW, tt;
    if (t < 50) { W = W0; Wp = Wp0; JW = 40; tt = t; }
    else        { W = W1; Wp = Wp1; JW = 64; tt = t - 50; }
    int jc = tt / 10, ic = tt - jc * 10;
    unsigned short outv[16];
    #pragma unroll
    for (int q = 0; q < 16; ++q) {
        int kl = h * 16 + q;
        int i = ic * 4 + (kl >> 3), j = jc * 8 + (kl & 7);
        outv[q] = f2h(W[((size_t)(i * JW + j)) * 128 + s]);
    }
    unsigned short* dst = Wp + (size_t)tt * 4096 + s * 32 + h * 16;
    *(uint4*)dst       = *(const uint4*)outv;        // kl h*16+0..7
    *(uint4*)(dst + 8) = *(const uint4*)(outv + 8);  // kl h*16+8..15
}

#define WBUF 20480   // halfwords per Wb buffer (5 tiles x 4096)

// One GEMM phase.  NJC jc-chunks; each jc = two 5-tile periods.  W staged in
// LDS (double-buffered 5-tile periods), one barrier per period.
template<int NJC>
__device__ __forceinline__ void gemm_phase(
    const unsigned short* __restrict__ Wp,   // [NJC*10][128][32] fp16, global
    const unsigned short* __restrict__ Jl,   // LDS j-source (Xl or NH)
    int jstride,                             // row stride of Jl in elems
    const unsigned int xi2[4][10],           // broadcast half2 of X[r, ic*4+kc]
    unsigned short* Wb,                      // LDS W double buffer [2][WBUF]
    f32x4 acc[4][4], int tid)
{
    constexpr int T = NJC * 10;
    const int lane = tid & 63;
    const int rt = (tid >> 6) & 3;           // row-tile (64 rows)
    const int sh = tid >> 8;                 // s-half (64 cols)
    const int ml = lane & 15;
    const int kc = lane >> 4;                // quad == k-chunk

    const unsigned short* jrow[4];
    #pragma unroll
    for (int mt = 0; mt < 4; ++mt)
        jrow[mt] = Jl + (rt * 64 + mt * 16 + ml) * jstride;

    const unsigned short* brd = Wb + (sh * 64 + ml) * 32 + kc * 8;
    unsigned short* bwr = Wb + tid * 8;      // staging slice (identity layout)

    uint4 wr[5];                             // next period's tiles (in regs)
    {   // prologue: period 0 -> buf0; period 1 -> regs
        uint4 w0[5];
        #pragma unroll
        for (int u = 0; u < 5; ++u)
            w0[u] = *(const uint4*)(Wp + (size_t)u * 4096 + tid * 8);
        #pragma unroll
        for (int u = 0; u < 5; ++u)
            *(uint4*)(bwr + u * 4096) = w0[u];          // buf0
        #pragma unroll
        for (int u = 0; u < 5; ++u)
            wr[u] = *(const uint4*)(Wp + (size_t)(5 + u) * 4096 + tid * 8);
    }
    __syncthreads();

    for (int jc2 = 0; jc2 < NJC; ++jc2) {
        // j-values for this jc (4 ds_reads; ~120cyc, covered by co-wave)
        uint4 jv[4];
        #pragma unroll
        for (int mt = 0; mt < 4; ++mt) jv[mt] = *(const uint4*)(jrow[mt] + jc2 * 8);

        #pragma unroll
        for (int half = 0; half < 2; ++half) {           // period p = jc2*2+half
            const int cb = half;                         // compute buffer
            const int nb = half ^ 1;                     // staging buffer
            const int t0 = jc2 * 10 + half * 5;          // this period's tiles
            // 1) stage next period's tiles (loaded one period ago; vmcnt free)
            #pragma unroll
            for (int u = 0; u < 5; ++u)
                *(uint4*)(bwr + nb * WBUF + u * 4096) = wr[u];
            // 2) issue loads for period p+2 (full period to land before drain)
            #pragma unroll
            for (int u = 0; u < 5; ++u) {
                int tl = t0 + 10 + u;
                if (tl >= T) tl = t0 + u;                // dead reload (tail)
                wr[u] = *(const uint4*)(Wp + (size_t)tl * 4096 + tid * 8);
            }
            // 3) compute this period from cb
            #pragma unroll
            for (int u = 0; u < 5; ++u) {
                const int ic = half * 5 + u;             // compile-time
                uint4 bv[4];
                #pragma unroll
                for (int nt = 0; nt < 4; ++nt)
                    bv[nt] = *(const uint4*)(brd + cb * WBUF + u * 4096 + nt * 512);
                uint4 av[4];
                #pragma unroll
                for (int mt = 0; mt < 4; ++mt) {
                    half2v x2 = __builtin_bit_cast(half2v, xi2[mt][ic]);
                    av[mt].x = __builtin_bit_cast(unsigned int,
                        (half2v)(x2 * __builtin_bit_cast(half2v, jv[mt].x)));
                    av[mt].y = __builtin_bit_cast(unsigned int,
                        (half2v)(x2 * __builtin_bit_cast(half2v, jv[mt].y)));
                    av[mt].z = __builtin_bit_cast(unsigned int,
                        (half2v)(x2 * __builtin_bit_cast(half2v, jv[mt].z)));
                    av[mt].w = __builtin_bit_cast(unsigned int,
                        (half2v)(x2 * __builtin_bit_cast(half2v, jv[mt].w)));
                }
                #pragma unroll
                for (int mt = 0; mt < 4; ++mt)
                    #pragma unroll
                    for (int nt = 0; nt < 4; ++nt)
                        acc[mt][nt] = __builtin_amdgcn_mfma_f32_16x16x32_f16(
                            __builtin_bit_cast(half8, av[mt]),
                            __builtin_bit_cast(half8, bv[nt]),
                            acc[mt][nt], 0, 0, 0);
            }
            __syncthreads();     // nb-writes visible; cb reads done; vm drained
        }
    }
}

__global__ __launch_bounds__(512, 2)
void fused_two_layer(const float* __restrict__ x,
                     const unsigned short* __restrict__ W0p,
                     const float* __restrict__ b0,
                     const unsigned short* __restrict__ W1p,
                     const float* __restrict__ b1,
                     float* __restrict__ out)
{
    __shared__ __align__(16) unsigned short Xl[256 * 40];   // 20.0 KB
    __shared__ __align__(16) unsigned short NH[256 * 72];   // 36.9 KB (stride 72
        // -> 144B rows: b128 j-reads 2-way max = free)
    __shared__ __align__(16) unsigned short Wb[2 * WBUF];   // 80.0 KB W dbuf

    const int tid  = threadIdx.x;
    const int lane = tid & 63;
    const int rt   = (tid >> 6) & 3;    // row-tile (64 rows)
    const int sh   = tid >> 8;          // s-half (64 cols)
    const int ml   = lane & 15;
    const int kc   = lane >> 4;

    // ---- stage X: x[8b][i][d] fp32 -> Xl[(bl*32+d)*40 + i] fp16 (RNE) ----
    const float* xblk = x + (size_t)blockIdx.x * (8 * 40 * 32);
    #pragma unroll
    for (int bl = 0; bl < 8; ++bl) {
        #pragma unroll
        for (int k = 0; k < 3; ++k) {
            int f = 512 * k + tid;
            if (f < 1280) {
                int i = f >> 5, d = f & 31;
                Xl[(bl * 32 + d) * 40 + i] = f2h(xblk[bl * 1280 + f]);
            }
        }
    }
    __syncthreads();

    // ---- preload this lane's i-scalars as broadcast half2 (both phases) ----
    unsigned int xi2[4][10];
    #pragma unroll
    for (int mt = 0; mt < 4; ++mt) {
        const unsigned short* xr = Xl + (rt * 64 + mt * 16 + ml) * 40;
        #pragma unroll
        for (int ic = 0; ic < 10; ++ic) {
            unsigned int u = xr[ic * 4 + kc];
            xi2[mt][ic] = u | (u << 16);
        }
    }

    f32x4 acc[4][4];
    const f32x4 zero4 = {0.f, 0.f, 0.f, 0.f};
    #pragma unroll
    for (int mt = 0; mt < 4; ++mt)
        #pragma unroll
        for (int nt = 0; nt < 4; ++nt) acc[mt][nt] = zero4;

    // ================= phase 0: 50 tiles, j from X =================
    gemm_phase<5>(W0p, Xl, 40, xi2, Wb, acc, tid);

    {   // epilogue 0: bias+relu; sh==0 (s<64) -> NH; sh==1 -> d-sum -> out[:,0:64]
        float bias[4];
        #pragma unroll
        for (int nt = 0; nt < 4; ++nt) bias[nt] = b0[sh * 64 + nt * 16 + ml];
        if (sh == 0) {
            #pragma unroll
            for (int mt = 0; mt < 4; ++mt) {
                int r = rt * 64 + mt * 16 + (kc << 2);
                #pragma unroll
                for (int nt = 0; nt < 4; ++nt) {
                    int s = nt * 16 + ml;
                    #pragma unroll
                    for (int rg = 0; rg < 4; ++rg) {
                        float v = fmaxf(acc[mt][nt][rg] + bias[nt], 0.0f);
                        NH[(r + rg) * 72 + s] = f2h(v);
                    }
                }
            }
        } else {
            int bb = blockIdx.x * 8 + rt * 2;
            #pragma unroll
            for (int nt = 0; nt < 4; ++nt) {
                float sA = 0.f, sB = 0.f;
                #pragma unroll
                for (int rg = 0; rg < 4; ++rg) {
                    sA += fmaxf(acc[0][nt][rg] + bias[nt], 0.f) + fmaxf(acc[1][nt][rg] + bias[nt], 0.f);
                    sB += fmaxf(acc[2][nt][rg] + bias[nt], 0.f) + fmaxf(acc[3][nt][rg] + bias[nt], 0.f);
                }
                sA = qsum(sA); sB = qsum(sB);
                if (lane < 16) {
                    int col = nt * 16 + lane;        // s-64
                    out[(size_t)bb * 192 + col]       = sA;
                    out[(size_t)(bb + 1) * 192 + col] = sB;
                }
            }
        }
    }
    __syncthreads();   // NH visible to all waves

    #pragma unroll
    for (int mt = 0; mt < 4; ++mt)
        #pragma unroll
        for (int nt = 0; nt < 4; ++nt) acc[mt][nt] = zero4;

    // ================= phase 1: 80 tiles, j from NH ================
    gemm_phase<8>(W1p, NH, 72, xi2, Wb, acc, tid);

    {   // epilogue 1: bias+relu; d-sum -> out[:, 64:192]
        float bias[4];
        #pragma unroll
        for (int nt = 0; nt < 4; ++nt) bias[nt] = b1[sh * 64 + nt * 16 + ml];
        int bb = blockIdx.x * 8 + rt * 2;
        #pragma unroll
        for (int nt = 0; nt < 4; ++nt) {
            float sA = 0.f, sB = 0.f;
            #pragma unroll
            for (int rg = 0; rg < 4; ++rg) {
                sA += fmaxf(acc[0][nt][rg] + bias[nt], 0.f) + fmaxf(acc[1][nt][rg] + bias[nt], 0.f);
                sB += fmaxf(acc[2][nt][rg] + bias[nt], 0.f) + fmaxf(acc[3][nt][rg] + bias[nt], 0.f);
            }
            sA = qsum(sA); sB = qsum(sB);
            if (lane < 16) {
                int col = 64 + sh * 64 + nt * 16 + lane;
                out[(size_t)bb * 192 + col]       = sA;
                out[(size_t)(bb + 1) * 192 + col] = sB;
            }
        }
    }
}

extern "C" void kernel_launch(void* const* d_in, const int* in_sizes, int n_in,
                              void* d_out, int out_size, void* d_ws, size_t ws_size,
                              hipStream_t stream) {
    const float* x  = (const float*)d_in[0];   // [2048][40][32]
    const float* W0 = (const float*)d_in[1];   // [40][40][128]
    const float* b0 = (const float*)d_in[2];   // [128]
    const float* W1 = (const float*)d_in[3];   // [40][64][128]
    const float* b1 = (const float*)d_in[4];   // [128]
    float* out = (float*)d_out;                // [2048][192]

    unsigned short* W0p = (unsigned short*)d_ws;                          // 50*4096*2 = 409600 B
    unsigned short* W1p = (unsigned short*)((char*)d_ws + 50 * 4096 * 2); // 80*4096*2 = 655360 B

    permute_w_both<<<130, 256, 0, stream>>>(W0, W1, W0p, W1p);
    fused_two_layer<<<256, 512, 0, stream>>>(x, W0p, b0, W1p, b1, out);
}

// Round 9
// 122.761 us; speedup vs baseline: 1.3066x; 1.3066x over previous
//
#include <hip/hip_runtime.h>
#include <stdint.h>

// ---------------------------------------------------------------------------
// B=2048, F0=40, D=32, LAYER0=LAYER1=128.  Rows r=b*32+d (65536).
//   phase0: h0[r,s] = relu(sum_{i<40,j<40} X[r,i]X[r,j] W0[i,j,s] + b0[s])
//   phase1: d1[r,s] = relu(sum_{i<40,j<64} X[r,i]NH[r,j] W1[i,j,s] + b1[s])
//   out[b,0:64] = sum_d h0[:,64:128]; out[b,64:192] = sum_d d1
//
// Round-9: r8's 5-tile/period barrier amortization WITHOUT register staging.
// r8 regressed via scratch spill (WRITE_SIZE 1.5->24MB: wr[5]+jv live across
// barriers, ~80B/thread x 2 phases ~= 21MB ✓).  Fix: W tiles go global->LDS
// via __builtin_amdgcn_global_load_lds (width 16) -- no VGPR round-trip.
// Staging layout is identity (tid*16 B) = the wave-uniform-base + lane*16
// DMA constraint.  Loads for period p+1 issue at the top of period p into
// the idle buffer and get a full ~2600-cyc period to land before the
// pre-barrier vmcnt(0) drain (26 barriers total, m97 mechanism amortized).
// Per-period/SIMD: MFMA 2576 cyc (limiter), LDS ~500, L2 15.5 B/cyc/CU.
// FP16 datapath: A-frag = one v_pk_mul_f16 per pair (xi2 broadcast * packed
// jv).  All xi2 indices compile-time (jc2/half/u nest).
// ---------------------------------------------------------------------------

typedef __attribute__((ext_vector_type(8))) _Float16 half8;
typedef __attribute__((ext_vector_type(2))) _Float16 half2v;
typedef __attribute__((ext_vector_type(4))) float f32x4;

__device__ __forceinline__ unsigned short f2h(float f) {   // v_cvt_f16_f32, RNE
    return __builtin_bit_cast(unsigned short, (_Float16)f);
}
__device__ __forceinline__ float qsum(float v) {  // reduce across row-quads
    v += __shfl_xor(v, 16, 64);
    v += __shfl_xor(v, 32, 64);
    return v;
}
// async global->LDS DMA, 16 B/lane.  lds dest = (wave-uniform base) + lane*16.
__device__ __forceinline__ void gl_lds16(const unsigned short* g, unsigned short* l) {
    __builtin_amdgcn_global_load_lds(
        (const __attribute__((address_space(1))) unsigned int*)g,
        (__attribute__((address_space(3))) unsigned int*)l,
        16, 0, 0);
}

// Permute W -> Wp[t][s][kl] fp16, t = jc*10+ic, kl = ii*8+jj, i=ic*4+ii,
// j=jc*8+jj.  One block per tile t; thread = (s, h) writes 32B contiguous.
__global__ void permute_w_both(const float* __restrict__ W0, const float* __restrict__ W1,
                               unsigned short* __restrict__ Wp0, unsigned short* __restrict__ Wp1)
{
    int t = blockIdx.x;
    int s = threadIdx.x >> 1, h = threadIdx.x & 1;
    const float* W; unsigned short* Wp; int JW, tt;
    if (t < 50) { W = W0; Wp = Wp0; JW = 40; tt = t; }
    else        { W = W1; Wp = Wp1; JW = 64; tt = t - 50; }
    int jc = tt / 10, ic = tt - jc * 10;
    unsigned short outv[16];
    #pragma unroll
    for (int q = 0; q < 16; ++q) {
        int kl = h * 16 + q;
        int i = ic * 4 + (kl >> 3), j = jc * 8 + (kl & 7);
        outv[q] = f2h(W[((size_t)(i * JW + j)) * 128 + s]);
    }
    unsigned short* dst = Wp + (size_t)tt * 4096 + s * 32 + h * 16;
    *(uint4*)dst       = *(const uint4*)outv;        // kl h*16+0..7
    *(uint4*)(dst + 8) = *(const uint4*)(outv + 8);  // kl h*16+8..15
}

#define WBUF 20480   // halfwords per Wb buffer (5 tiles x 4096)

// One GEMM phase.  NJC jc-chunks; each jc = two 5-tile periods.  W staged in
// LDS via global_load_lds (double-buffered periods), one barrier per period.
template<int NJC>
__device__ __forceinline__ void gemm_phase(
    const unsigned short* __restrict__ Wp,   // [NJC*10][128][32] fp16, global
    const unsigned short* __restrict__ Jl,   // LDS j-source (Xl or NH)
    int jstride,                             // row stride of Jl in elems
    const unsigned int xi2[4][10],           // broadcast half2 of X[r, ic*4+kc]
    unsigned short* Wb,                      // LDS W double buffer [2][WBUF]
    f32x4 acc[4][4], int tid)
{
    constexpr int T = NJC * 10;
    const int lane = tid & 63;
    const int wv = tid >> 6;                 // wave id 0..7
    const int rt = wv & 3;                   // row-tile (64 rows)
    const int sh = tid >> 8;                 // s-half (64 cols)
    const int ml = lane & 15;
    const int kc = lane >> 4;                // quad == k-chunk

    const unsigned short* jrow[4];
    #pragma unroll
    for (int mt = 0; mt < 4; ++mt)
        jrow[mt] = Jl + (rt * 64 + mt * 16 + ml) * jstride;

    const unsigned short* brd = Wb + (sh * 64 + ml) * 32 + kc * 8;
    // DMA: global src per-lane = Wp + tile*4096 + tid*8 (halfwords);
    //      LDS dest wave-uniform = Wb + buf*WBUF + u*4096 + wv*512.
    const unsigned short* gsrc = Wp + tid * 8;
    unsigned short* ldst = Wb + wv * 512;

    auto stage_period = [&](int buf, int t0) {   // issue 5 tile DMAs
        #pragma unroll
        for (int u = 0; u < 5; ++u)
            gl_lds16(gsrc + (size_t)(t0 + u) * 4096, ldst + buf * WBUF + u * 4096);
    };

    stage_period(0, 0);          // period 0 -> buf0
    __syncthreads();             // vmcnt(0) drain: tiles landed

    for (int jc2 = 0; jc2 < NJC; ++jc2) {
        uint4 jv[4];             // this jc's j-values (4 ds_read_b128)
        #pragma unroll
        for (int mt = 0; mt < 4; ++mt) jv[mt] = *(const uint4*)(jrow[mt] + jc2 * 8);

        #pragma unroll
        for (int half = 0; half < 2; ++half) {           // period p = jc2*2+half
            const int p  = jc2 * 2 + half;
            const int cb = p & 1;                        // compute buffer
            const int nb = cb ^ 1;
            if ((p + 1) * 5 < T) stage_period(nb, (p + 1) * 5);  // full period to land
            #pragma unroll
            for (int u = 0; u < 5; ++u) {
                const int ic = half * 5 + u;             // compile-time
                uint4 bv[4];
                #pragma unroll
                for (int nt = 0; nt < 4; ++nt)
                    bv[nt] = *(const uint4*)(brd + cb * WBUF + u * 4096 + nt * 512);
                uint4 av[4];
                #pragma unroll
                for (int mt = 0; mt < 4; ++mt) {
                    half2v x2 = __builtin_bit_cast(half2v, xi2[mt][ic]);
                    av[mt].x = __builtin_bit_cast(unsigned int,
                        (half2v)(x2 * __builtin_bit_cast(half2v, jv[mt].x)));
                    av[mt].y = __builtin_bit_cast(unsigned int,
                        (half2v)(x2 * __builtin_bit_cast(half2v, jv[mt].y)));
                    av[mt].z = __builtin_bit_cast(unsigned int,
                        (half2v)(x2 * __builtin_bit_cast(half2v, jv[mt].z)));
                    av[mt].w = __builtin_bit_cast(unsigned int,
                        (half2v)(x2 * __builtin_bit_cast(half2v, jv[mt].w)));
                }
                #pragma unroll
                for (int mt = 0; mt < 4; ++mt)
                    #pragma unroll
                    for (int nt = 0; nt < 4; ++nt)
                        acc[mt][nt] = __builtin_amdgcn_mfma_f32_16x16x32_f16(
                            __builtin_bit_cast(half8, av[mt]),
                            __builtin_bit_cast(half8, bv[nt]),
                            acc[mt][nt], 0, 0, 0);
            }
            __syncthreads();     // nb DMA landed; cb reads done
        }
    }
}

__global__ __launch_bounds__(512, 2)
void fused_two_layer(const float* __restrict__ x,
                     const unsigned short* __restrict__ W0p,
                     const float* __restrict__ b0,
                     const unsigned short* __restrict__ W1p,
                     const float* __restrict__ b1,
                     float* __restrict__ out)
{
    __shared__ __align__(16) unsigned short Xl[256 * 40];   // 20.0 KB
    __shared__ __align__(16) unsigned short NH[256 * 72];   // 36.9 KB (stride 72
        // -> 144B rows: b128 j-reads 2-way max = free)
    __shared__ __align__(16) unsigned short Wb[2 * WBUF];   // 80.0 KB W dbuf

    const int tid  = threadIdx.x;
    const int lane = tid & 63;
    const int rt   = (tid >> 6) & 3;    // row-tile (64 rows)
    const int sh   = tid >> 8;          // s-half (64 cols)
    const int ml   = lane & 15;
    const int kc   = lane >> 4;

    // ---- stage X: x[8b][i][d] fp32 -> Xl[(bl*32+d)*40 + i] fp16 (RNE) ----
    const float* xblk = x + (size_t)blockIdx.x * (8 * 40 * 32);
    #pragma unroll
    for (int bl = 0; bl < 8; ++bl) {
        #pragma unroll
        for (int k = 0; k < 3; ++k) {
            int f = 512 * k + tid;
            if (f < 1280) {
                int i = f >> 5, d = f & 31;
                Xl[(bl * 32 + d) * 40 + i] = f2h(xblk[bl * 1280 + f]);
            }
        }
    }
    __syncthreads();

    // ---- preload this lane's i-scalars as broadcast half2 (both phases) ----
    unsigned int xi2[4][10];
    #pragma unroll
    for (int mt = 0; mt < 4; ++mt) {
        const unsigned short* xr = Xl + (rt * 64 + mt * 16 + ml) * 40;
        #pragma unroll
        for (int ic = 0; ic < 10; ++ic) {
            unsigned int u = xr[ic * 4 + kc];
            xi2[mt][ic] = u | (u << 16);
        }
    }

    f32x4 acc[4][4];
    const f32x4 zero4 = {0.f, 0.f, 0.f, 0.f};
    #pragma unroll
    for (int mt = 0; mt < 4; ++mt)
        #pragma unroll
        for (int nt = 0; nt < 4; ++nt) acc[mt][nt] = zero4;

    // ================= phase 0: 50 tiles, j from X =================
    gemm_phase<5>(W0p, Xl, 40, xi2, Wb, acc, tid);

    {   // epilogue 0: bias+relu; sh==0 (s<64) -> NH; sh==1 -> d-sum -> out[:,0:64]
        float bias[4];
        #pragma unroll
        for (int nt = 0; nt < 4; ++nt) bias[nt] = b0[sh * 64 + nt * 16 + ml];
        if (sh == 0) {
            #pragma unroll
            for (int mt = 0; mt < 4; ++mt) {
                int r = rt * 64 + mt * 16 + (kc << 2);
                #pragma unroll
                for (int nt = 0; nt < 4; ++nt) {
                    int s = nt * 16 + ml;
                    #pragma unroll
                    for (int rg = 0; rg < 4; ++rg) {
                        float v = fmaxf(acc[mt][nt][rg] + bias[nt], 0.0f);
                        NH[(r + rg) * 72 + s] = f2h(v);
                    }
                }
            }
        } else {
            int bb = blockIdx.x * 8 + rt * 2;
            #pragma unroll
            for (int nt = 0; nt < 4; ++nt) {
                float sA = 0.f, sB = 0.f;
                #pragma unroll
                for (int rg = 0; rg < 4; ++rg) {
                    sA += fmaxf(acc[0][nt][rg] + bias[nt], 0.f) + fmaxf(acc[1][nt][rg] + bias[nt], 0.f);
                    sB += fmaxf(acc[2][nt][rg] + bias[nt], 0.f) + fmaxf(acc[3][nt][rg] + bias[nt], 0.f);
                }
                sA = qsum(sA); sB = qsum(sB);
                if (lane < 16) {
                    int col = nt * 16 + lane;        // s-64
                    out[(size_t)bb * 192 + col]       = sA;
                    out[(size_t)(bb + 1) * 192 + col] = sB;
                }
            }
        }
    }
    __syncthreads();   // NH visible to all waves

    #pragma unroll
    for (int mt = 0; mt < 4; ++mt)
        #pragma unroll
        for (int nt = 0; nt < 4; ++nt) acc[mt][nt] = zero4;

    // ================= phase 1: 80 tiles, j from NH ================
    gemm_phase<8>(W1p, NH, 72, xi2, Wb, acc, tid);

    {   // epilogue 1: bias+relu; d-sum -> out[:, 64:192]
        float bias[4];
        #pragma unroll
        for (int nt = 0; nt < 4; ++nt) bias[nt] = b1[sh * 64 + nt * 16 + ml];
        int bb = blockIdx.x * 8 + rt * 2;
        #pragma unroll
        for (int nt = 0; nt < 4; ++nt) {
            float sA = 0.f, sB = 0.f;
            #pragma unroll
            for (int rg = 0; rg < 4; ++rg) {
                sA += fmaxf(acc[0][nt][rg] + bias[nt], 0.f) + fmaxf(acc[1][nt][rg] + bias[nt], 0.f);
                sB += fmaxf(acc[2][nt][rg] + bias[nt], 0.f) + fmaxf(acc[3][nt][rg] + bias[nt], 0.f);
            }
            sA = qsum(sA); sB = qsum(sB);
            if (lane < 16) {
                int col = 64 + sh * 64 + nt * 16 + lane;
                out[(size_t)bb * 192 + col]       = sA;
                out[(size_t)(bb + 1) * 192 + col] = sB;
            }
        }
    }
}

extern "C" void kernel_launch(void* const* d_in, const int* in_sizes, int n_in,
                              void* d_out, int out_size, void* d_ws, size_t ws_size,
                              hipStream_t stream) {
    const float* x  = (const float*)d_in[0];   // [2048][40][32]
    const float* W0 = (const float*)d_in[1];   // [40][40][128]
    const float* b0 = (const float*)d_in[2];   // [128]
    const float* W1 = (const float*)d_in[3];   // [40][64][128]
    const float* b1 = (const float*)d_in[4];   // [128]
    float* out = (float*)d_out;                // [2048][192]

    unsigned short* W0p = (unsigned short*)d_ws;                          // 50*4096*2 = 409600 B
    unsigned short* W1p = (unsigned short*)((char*)d_ws + 50 * 4096 * 2); // 80*4096*2 = 655360 B

    permute_w_both<<<130, 256, 0, stream>>>(W0, W1, W0p, W1p);
    fused_two_layer<<<256, 512, 0, stream>>>(x, W0p, b0, W1p, b1, out);
}